// Round 1
// baseline (623.145 us; speedup 1.0000x reference)
//
#include <hip/hip_runtime.h>
#include <hip/hip_bf16.h>
#include <math.h>

#define NF 32
#define NH 8
#define NP 6

// ---------------- batchnorm stats: one block per feature ----------------
__global__ void bn_stats_kernel(const float* __restrict__ src,
                                const float* __restrict__ g,
                                const float* __restrict__ b,
                                float* __restrict__ scale,
                                float* __restrict__ shift,
                                int nrows, int nfeat) {
    int f = blockIdx.x;
    int tid = threadIdx.x;
    float s = 0.f, sq = 0.f;
    for (int r = tid; r < nrows; r += blockDim.x) {
        float v = src[(size_t)r * nfeat + f];
        s += v;
        sq += v * v;
    }
    __shared__ float ls[256], lq[256];
    ls[tid] = s; lq[tid] = sq;
    __syncthreads();
    for (int st = 128; st > 0; st >>= 1) {
        if (tid < st) { ls[tid] += ls[tid + st]; lq[tid] += lq[tid + st]; }
        __syncthreads();
    }
    if (tid == 0) {
        float inv_n = 1.0f / (float)nrows;
        float m = ls[0] * inv_n;
        float var = lq[0] * inv_n - m * m;
        float rstd = rsqrtf(var + 1e-5f);
        float sc = g[f] * rstd;
        scale[f] = sc;
        shift[f] = b[f] - m * sc;
    }
}

// ---------------- layer 1: bn0(features) @ W1.T + b1 ----------------
__global__ void mlp1_kernel(const float* __restrict__ feat,
                            const float* __restrict__ scale,
                            const float* __restrict__ shift,
                            const float* __restrict__ W1,
                            const float* __restrict__ b1,
                            float* __restrict__ h1, int B) {
    int r = blockIdx.x * blockDim.x + threadIdx.x;
    if (r >= B) return;
    float x[NF];
#pragma unroll
    for (int i = 0; i < NF; i++)
        x[i] = feat[(size_t)r * NF + i] * scale[i] + shift[i];
#pragma unroll
    for (int o = 0; o < NH; o++) {
        float acc = b1[o];
#pragma unroll
        for (int i = 0; i < NF; i++) acc += W1[o * NF + i] * x[i];
        h1[(size_t)r * NH + o] = acc;
    }
}

// ---------------- layer 2: relu(bn(h)) @ W.T + b (8 -> 8) ----------------
__global__ void mlp_mid_kernel(const float* __restrict__ hin,
                               const float* __restrict__ scale,
                               const float* __restrict__ shift,
                               const float* __restrict__ W,
                               const float* __restrict__ bb,
                               float* __restrict__ hout, int B) {
    int r = blockIdx.x * blockDim.x + threadIdx.x;
    if (r >= B) return;
    float x[NH];
#pragma unroll
    for (int i = 0; i < NH; i++) {
        float v = hin[(size_t)r * NH + i] * scale[i] + shift[i];
        x[i] = fmaxf(v, 0.0f);
    }
#pragma unroll
    for (int o = 0; o < NH; o++) {
        float acc = bb[o];
#pragma unroll
        for (int i = 0; i < NH; i++) acc += W[o * NH + i] * x[i];
        hout[(size_t)r * NH + o] = acc;
    }
}

// ---------------- layer 3 + sigmoid limits + per-row scan constants ----------------
__global__ void params_kernel(const float* __restrict__ h2,
                              const float* __restrict__ scale,
                              const float* __restrict__ shift,
                              const float* __restrict__ W3,
                              const float* __restrict__ b3,
                              const float* __restrict__ pn,
                              float* __restrict__ rowp, int B, int T) {
    int r = blockIdx.x * blockDim.x + threadIdx.x;
    if (r >= B) return;
    float x[NH];
#pragma unroll
    for (int i = 0; i < NH; i++) {
        float v = h2[(size_t)r * NH + i] * scale[i] + shift[i];
        x[i] = fmaxf(v, 0.0f);
    }
    const float lo[NP] = {0.5f, 0.01f, 0.0f, 0.0f, 0.0f, 0.01f};
    const float hi[NP] = {5.0f, 0.5f, 2.0f, 2.0f, 1.0f, 0.5f};
    float p[NP];
#pragma unroll
    for (int j = 0; j < NP; j++) {
        float cr = b3[j] + pn[j];
#pragma unroll
        for (int i = 0; i < NH; i++) cr += W3[j * NH + i] * x[i];
        float sg = 1.0f / (1.0f + expf(-cr));
        p[j] = lo[j] + (hi[j] - lo[j]) * sg;
    }
    float f_start = p[0], f_inf = p[1], f_decay = p[2], f_T = p[3];
    float w_offset = p[4], w_T = p[5];
    float df = f_start - f_inf;
    // base = 0.7 * 0.1^f_decay ; f_t = f_inf + df * base^((t/T)/(10*0.1^f_T))
    //      = f_inf + df * exp2(k * t),  k = log2(base)/(T * 10 * 0.1^f_T)
    const float LOG2_0p7 = -0.5145731728297583f;
    const float LOG2_0p1 = -3.3219280948873623f;
    const float LOG2_10 = 3.3219280948873623f;
    float log2base = LOG2_0p7 + f_decay * LOG2_0p1;
    float invden = 0.1f * exp2f(LOG2_10 * f_T); // = 1/(10*0.1^f_T)
    float k = log2base * invden / (float)T;
    // w_t = sigmoid(t*wscale + wbias)
    float wscale = 1.0f / ((float)T * w_T);
    float wbias = -w_offset / w_T;
    float* rp = rowp + (size_t)r * 8;
    rp[0] = f_inf; rp[1] = df; rp[2] = k; rp[3] = wscale; rp[4] = wbias;
    rp[5] = 0.f; rp[6] = 0.f; rp[7] = 0.f;
}

// ---------------- sequential IIR scan, one thread per row ----------------
__global__ void scan_kernel(const float* __restrict__ X,
                            const float* __restrict__ rowp,
                            const float* __restrict__ Fp,
                            float* __restrict__ out, int B, int T) {
    int r = blockIdx.x * blockDim.x + threadIdx.x;
    if (r >= B) return;
    const float* rp = rowp + (size_t)r * 8;
    float f_inf = rp[0], df = rp[1], k = rp[2], wsc = rp[3], wb = rp[4];
    float F = Fp[0];
    float c = sqrtf(exp2f(1.0f / 3.0f) - 1.0f) * F * (1.0f / 3.14159265358979323846f);
    const float* Xr = X + (size_t)r * T;

    float x0 = Xr[0];
    float w0 = 1.0f / (1.0f + expf(-wb)); // t = 0
    float y1 = x0, y2 = x0, xp = x0;
    float acc = w0 * x0;
    float wsum = w0;
    for (int t = 1; t < T; t++) {
        float tf = (float)t;
        float ft = f_inf + df * exp2f(k * tf);
        float z = wsc * tf + wb;
        float wt = 1.0f / (1.0f + expf(-z));
        float at = (ft - c) / (ft + c);
        float bt = 0.5f * (at + 1.0f);
        float x = Xr[t];
        float y1n = bt * (x + xp) - at * y1;
        float y2n = bt * (y1n + y1) - at * y2;
        acc += wt * y2n;
        wsum += wt;
        y1 = y1n; y2 = y2n; xp = x;
    }
    out[r] = acc / wsum;
}

extern "C" void kernel_launch(void* const* d_in, const int* in_sizes, int n_in,
                              void* d_out, int out_size, void* d_ws, size_t ws_size,
                              hipStream_t stream) {
    const float* X = (const float*)d_in[0];
    const float* features = (const float*)d_in[1];
    const float* Fp = (const float*)d_in[2];
    const float* bn0_g = (const float*)d_in[3];
    const float* bn0_b = (const float*)d_in[4];
    const float* W1 = (const float*)d_in[5];
    const float* b1 = (const float*)d_in[6];
    const float* bn1_g = (const float*)d_in[7];
    const float* bn1_b = (const float*)d_in[8];
    const float* W2 = (const float*)d_in[9];
    const float* b2 = (const float*)d_in[10];
    const float* bn2_g = (const float*)d_in[11];
    const float* bn2_b = (const float*)d_in[12];
    const float* W3 = (const float*)d_in[13];
    const float* b3 = (const float*)d_in[14];
    const float* pn = (const float*)d_in[15];
    float* out = (float*)d_out;

    const int B = in_sizes[1] / NF;      // 2048
    const int T = in_sizes[0] / B;       // 4096

    float* ws = (float*)d_ws;
    float* s0 = ws + 0;           // 32
    float* h0 = ws + 32;          // 32
    float* s1 = ws + 64;          // 8
    float* sh1 = ws + 72;         // 8
    float* s2 = ws + 80;          // 8
    float* sh2 = ws + 88;         // 8
    float* h1buf = ws + 96;                   // B*8
    float* h2buf = h1buf + (size_t)B * NH;    // B*8
    float* rowp = h2buf + (size_t)B * NH;     // B*8

    int rb = 256;
    int rgrid = (B + rb - 1) / rb;

    bn_stats_kernel<<<NF, 256, 0, stream>>>(features, bn0_g, bn0_b, s0, h0, B, NF);
    mlp1_kernel<<<rgrid, rb, 0, stream>>>(features, s0, h0, W1, b1, h1buf, B);
    bn_stats_kernel<<<NH, 256, 0, stream>>>(h1buf, bn1_g, bn1_b, s1, sh1, B, NH);
    mlp_mid_kernel<<<rgrid, rb, 0, stream>>>(h1buf, s1, sh1, W2, b2, h2buf, B);
    bn_stats_kernel<<<NH, 256, 0, stream>>>(h2buf, bn2_g, bn2_b, s2, sh2, B, NH);
    params_kernel<<<rgrid, rb, 0, stream>>>(h2buf, s2, sh2, W3, b3, pn, rowp, B, T);

    int sb = 64;
    int sgrid = (B + sb - 1) / sb;
    scan_kernel<<<sgrid, sb, 0, stream>>>(X, rowp, Fp, out, B, T);
}

// Round 2
// 247.614 us; speedup vs baseline: 2.5166x; 2.5166x over previous
//
#include <hip/hip_runtime.h>
#include <hip/hip_bf16.h>
#include <math.h>

#define NF 32
#define NH 8
#define NP 6

// ==================== fused MLP: one block, 1024 threads ====================
__global__ __launch_bounds__(1024) void mlp_fused_kernel(
    const float* __restrict__ features,
    const float* __restrict__ bn0_g, const float* __restrict__ bn0_b,
    const float* __restrict__ W1, const float* __restrict__ b1,
    const float* __restrict__ bn1_g, const float* __restrict__ bn1_b,
    const float* __restrict__ W2, const float* __restrict__ b2,
    const float* __restrict__ bn2_g, const float* __restrict__ bn2_b,
    const float* __restrict__ W3, const float* __restrict__ b3,
    const float* __restrict__ pn,
    float* __restrict__ h1buf, float* __restrict__ h2buf,
    float* __restrict__ rowp, int B, int T)
{
    __shared__ float red[1024];
    __shared__ float red2[1024];
    __shared__ float sc0[NF], sh0[NF];
    __shared__ float sc1[NH], shf1[NH];
    __shared__ float sc2[NH], shf2[NH];
    __shared__ float sW1[NH * NF], sb1[NH];
    __shared__ float sW2[NH * NH], sb2[NH];
    __shared__ float sW3[NP * NH], sb3[NP], spn[NP];

    const int tid = threadIdx.x;

    // ---- preload weights into LDS ----
    if (tid < NH * NF) sW1[tid] = W1[tid];
    if (tid < NH) sb1[tid] = b1[tid];
    if (tid >= 256 && tid < 256 + NH * NH) sW2[tid - 256] = W2[tid - 256];
    if (tid >= 384 && tid < 384 + NH) sb2[tid - 384] = b2[tid - 384];
    if (tid >= 512 && tid < 512 + NP * NH) sW3[tid - 512] = W3[tid - 512];
    if (tid >= 576 && tid < 576 + NP) sb3[tid - 576] = b3[tid - 576];
    if (tid >= 640 && tid < 640 + NP) spn[tid - 640] = pn[tid - 640];

    // ---- bn0 stats: f = tid&31, chunk = tid>>5 ----
    {
        int f = tid & 31;
        int cid = tid >> 5;
        float s = 0.f, q = 0.f;
        for (int r = cid; r < B; r += 32) {
            float v = features[(size_t)r * NF + f];
            s += v; q += v * v;
        }
        red[tid] = s; red2[tid] = q;
    }
    __syncthreads();
    if (tid < NF) {
        float s = 0.f, q = 0.f;
        for (int c2 = 0; c2 < 32; c2++) { s += red[c2 * 32 + tid]; q += red2[c2 * 32 + tid]; }
        float inv_n = 1.0f / (float)B;
        float m = s * inv_n;
        float var = q * inv_n - m * m;
        float sc = bn0_g[tid] * rsqrtf(var + 1e-5f);
        sc0[tid] = sc;
        sh0[tid] = bn0_b[tid] - m * sc;
    }
    __syncthreads();

    // ---- h1 = bn0(feat) @ W1.T + b1 ----
    for (int r = tid; r < B; r += 1024) {
        float x[NF];
#pragma unroll
        for (int i = 0; i < NF; i++)
            x[i] = features[(size_t)r * NF + i] * sc0[i] + sh0[i];
#pragma unroll
        for (int o = 0; o < NH; o++) {
            float acc = sb1[o];
#pragma unroll
            for (int i = 0; i < NF; i++) acc = fmaf(sW1[o * NF + i], x[i], acc);
            h1buf[(size_t)r * NH + o] = acc;
        }
    }
    __syncthreads();

    // ---- bn1 stats ----
    {
        int f = tid & 7;
        int cid = tid >> 3;
        float s = 0.f, q = 0.f;
        for (int r = cid; r < B; r += 128) {
            float v = h1buf[(size_t)r * NH + f];
            s += v; q += v * v;
        }
        red[tid] = s; red2[tid] = q;
    }
    __syncthreads();
    if (tid < NH) {
        float s = 0.f, q = 0.f;
        for (int c2 = 0; c2 < 128; c2++) { s += red[c2 * 8 + tid]; q += red2[c2 * 8 + tid]; }
        float inv_n = 1.0f / (float)B;
        float m = s * inv_n;
        float var = q * inv_n - m * m;
        float sc = bn1_g[tid] * rsqrtf(var + 1e-5f);
        sc1[tid] = sc;
        shf1[tid] = bn1_b[tid] - m * sc;
    }
    __syncthreads();

    // ---- h2 = relu(bn1(h1)) @ W2.T + b2 ----
    for (int r = tid; r < B; r += 1024) {
        float x[NH];
#pragma unroll
        for (int i = 0; i < NH; i++) {
            float v = h1buf[(size_t)r * NH + i] * sc1[i] + shf1[i];
            x[i] = fmaxf(v, 0.0f);
        }
#pragma unroll
        for (int o = 0; o < NH; o++) {
            float acc = sb2[o];
#pragma unroll
            for (int i = 0; i < NH; i++) acc = fmaf(sW2[o * NH + i], x[i], acc);
            h2buf[(size_t)r * NH + o] = acc;
        }
    }
    __syncthreads();

    // ---- bn2 stats ----
    {
        int f = tid & 7;
        int cid = tid >> 3;
        float s = 0.f, q = 0.f;
        for (int r = cid; r < B; r += 128) {
            float v = h2buf[(size_t)r * NH + f];
            s += v; q += v * v;
        }
        red[tid] = s; red2[tid] = q;
    }
    __syncthreads();
    if (tid < NH) {
        float s = 0.f, q = 0.f;
        for (int c2 = 0; c2 < 128; c2++) { s += red[c2 * 8 + tid]; q += red2[c2 * 8 + tid]; }
        float inv_n = 1.0f / (float)B;
        float m = s * inv_n;
        float var = q * inv_n - m * m;
        float sc = bn2_g[tid] * rsqrtf(var + 1e-5f);
        sc2[tid] = sc;
        shf2[tid] = bn2_b[tid] - m * sc;
    }
    __syncthreads();

    // ---- params per row ----
    const float lo[NP] = {0.5f, 0.01f, 0.0f, 0.0f, 0.0f, 0.01f};
    const float hi[NP] = {5.0f, 0.5f, 2.0f, 2.0f, 1.0f, 0.5f};
    for (int r = tid; r < B; r += 1024) {
        float x[NH];
#pragma unroll
        for (int i = 0; i < NH; i++) {
            float v = h2buf[(size_t)r * NH + i] * sc2[i] + shf2[i];
            x[i] = fmaxf(v, 0.0f);
        }
        float p[NP];
#pragma unroll
        for (int j = 0; j < NP; j++) {
            float cr = sb3[j] + spn[j];
#pragma unroll
            for (int i = 0; i < NH; i++) cr = fmaf(sW3[j * NH + i], x[i], cr);
            float sg = 1.0f / (1.0f + expf(-cr));
            p[j] = lo[j] + (hi[j] - lo[j]) * sg;
        }
        float f_start = p[0], f_inf = p[1], f_decay = p[2], f_T = p[3];
        float w_offset = p[4], w_T = p[5];
        float df = f_start - f_inf;
        const float LOG2_0p7 = -0.5145731728297583f;
        const float LOG2_0p1 = -3.3219280948873623f;
        const float LOG2_10 = 3.3219280948873623f;
        float log2base = LOG2_0p7 + f_decay * LOG2_0p1;
        float invden = 0.1f * exp2f(LOG2_10 * f_T);
        float k = log2base * invden / (float)T;
        float wscale = 1.0f / ((float)T * w_T);
        float wbias = -w_offset / w_T;
        float* rp = rowp + (size_t)r * 8;
        rp[0] = f_inf; rp[1] = df; rp[2] = k; rp[3] = wscale; rp[4] = wbias;
        rp[5] = 0.f; rp[6] = 0.f; rp[7] = 0.f;
    }
}

// ==================== parallel scan: one wave per row ====================
// State s=(y1,y2); step t>=1: s = [[-a,0],[g,-a]] s + (u, b*u), g=b(1-a), u=b(x_t+x_{t-1})
// t==0 "reset": M=0, V=(x0,x0). Composites closed under [[P,0],[Q,P]] + (V1,V2).
__global__ __launch_bounds__(256) void scan_kernel(
    const float* __restrict__ X,
    const float* __restrict__ rowp,
    const float* __restrict__ Fp,
    float* __restrict__ out, int B, int T)
{
    const int lane = threadIdx.x & 63;
    const int r = blockIdx.x * 4 + (threadIdx.x >> 6);
    if (r >= B) return;

    const float* rp = rowp + (size_t)r * 8;
    const float f_inf = rp[0], df = rp[1], k = rp[2], wsc = rp[3], wb = rp[4];
    const float F = Fp[0];
    const float c = sqrtf(exp2f(1.0f / 3.0f) - 1.0f) * F * (1.0f / 3.14159265358979323846f);
    const float c2 = 2.0f * c;

    const int C = T >> 6;          // steps per lane (64)
    const int t0 = lane * C;
    const float* Xr = X + (size_t)r * T;
    const float4* Xr4 = reinterpret_cast<const float4*>(Xr + t0);

    const float ek = exp2f(k);

    // ---------- pass 1: per-lane affine composite ----------
    float P = 1.f, Q = 0.f, V1 = 0.f, V2 = 0.f;
    {
        float e = exp2f(k * (float)t0);
        float xp = (lane == 0) ? 0.f : Xr[t0 - 1];
        for (int j = 0; j < C / 4; j++) {
            float4 xq = Xr4[j];
            float xs[4] = {xq.x, xq.y, xq.z, xq.w};
#pragma unroll
            for (int m = 0; m < 4; m++) {
                int t = t0 + j * 4 + m;
                float x = xs[m];
                if (t == 0) {
                    P = 0.f; Q = 0.f; V1 = x; V2 = x;
                } else {
                    float ft = fmaf(df, e, f_inf);
                    float inv = __builtin_amdgcn_rcpf(ft + c);
                    float a = fmaf(-c2, inv, 1.0f);
                    float b = fmaf(-c, inv, 1.0f);
                    float u = b * (x + xp);
                    float g = b * c2 * inv;   // b*(1-a)
                    float Pn = -a * P;
                    float Qn = fmaf(g, P, -a * Q);
                    float V1n = fmaf(-a, V1, u);
                    float V2n = fmaf(g, V1, fmaf(-a, V2, b * u));
                    P = Pn; Q = Qn; V1 = V1n; V2 = V2n;
                }
                e *= ek;
                xp = x;
            }
        }
    }

    // ---------- inclusive scan across lanes (compose: mine after other) ----------
#pragma unroll
    for (int d = 1; d < 64; d <<= 1) {
        float Po = __shfl_up(P, d);
        float Qo = __shfl_up(Q, d);
        float V1o = __shfl_up(V1, d);
        float V2o = __shfl_up(V2, d);
        if (lane >= d) {
            float Pn = P * Po;
            float Qn = fmaf(Q, Po, P * Qo);
            float V1n = fmaf(P, V1o, V1);
            float V2n = fmaf(Q, V1o, fmaf(P, V2o, V2));
            P = Pn; Q = Qn; V1 = V1n; V2 = V2n;
        }
    }
    float y1 = __shfl_up(V1, 1);
    float y2 = __shfl_up(V2, 1);
    if (lane == 0) { y1 = 0.f; y2 = 0.f; }

    // ---------- pass 2: replay with real state, accumulate ----------
    float acc = 0.f, wsum = 0.f;
    {
        float e = exp2f(k * (float)t0);
        float E = expf(-(wsc * (float)t0 + wb));
        float er = expf(-wsc);
        float xp = (lane == 0) ? 0.f : Xr[t0 - 1];
        for (int j = 0; j < C / 4; j++) {
            float4 xq = Xr4[j];
            float xs[4] = {xq.x, xq.y, xq.z, xq.w};
#pragma unroll
            for (int m = 0; m < 4; m++) {
                int t = t0 + j * 4 + m;
                float x = xs[m];
                float w = __builtin_amdgcn_rcpf(1.0f + E);
                if (t == 0) {
                    y1 = x; y2 = x;
                } else {
                    float ft = fmaf(df, e, f_inf);
                    float inv = __builtin_amdgcn_rcpf(ft + c);
                    float a = fmaf(-c2, inv, 1.0f);
                    float b = fmaf(-c, inv, 1.0f);
                    float y1n = fmaf(b, x + xp, -a * y1);
                    float y2n = fmaf(b, y1n + y1, -a * y2);
                    y1 = y1n; y2 = y2n;
                }
                acc = fmaf(w, y2, acc);
                wsum += w;
                e *= ek;
                E *= er;
                xp = x;
            }
        }
    }

    // ---------- wave reduction ----------
#pragma unroll
    for (int d = 1; d < 64; d <<= 1) {
        acc += __shfl_xor(acc, d);
        wsum += __shfl_xor(wsum, d);
    }
    if (lane == 0) out[r] = acc / wsum;
}

extern "C" void kernel_launch(void* const* d_in, const int* in_sizes, int n_in,
                              void* d_out, int out_size, void* d_ws, size_t ws_size,
                              hipStream_t stream) {
    const float* X = (const float*)d_in[0];
    const float* features = (const float*)d_in[1];
    const float* Fp = (const float*)d_in[2];
    const float* bn0_g = (const float*)d_in[3];
    const float* bn0_b = (const float*)d_in[4];
    const float* W1 = (const float*)d_in[5];
    const float* b1 = (const float*)d_in[6];
    const float* bn1_g = (const float*)d_in[7];
    const float* bn1_b = (const float*)d_in[8];
    const float* W2 = (const float*)d_in[9];
    const float* b2 = (const float*)d_in[10];
    const float* bn2_g = (const float*)d_in[11];
    const float* bn2_b = (const float*)d_in[12];
    const float* W3 = (const float*)d_in[13];
    const float* b3 = (const float*)d_in[14];
    const float* pn = (const float*)d_in[15];
    float* out = (float*)d_out;

    const int B = in_sizes[1] / NF;      // 2048
    const int T = in_sizes[0] / B;       // 4096

    float* ws = (float*)d_ws;
    float* h1buf = ws;                        // B*8
    float* h2buf = h1buf + (size_t)B * NH;    // B*8
    float* rowp = h2buf + (size_t)B * NH;     // B*8

    mlp_fused_kernel<<<1, 1024, 0, stream>>>(features, bn0_g, bn0_b, W1, b1,
                                             bn1_g, bn1_b, W2, b2, bn2_g, bn2_b,
                                             W3, b3, pn, h1buf, h2buf, rowp, B, T);

    scan_kernel<<<(B + 3) / 4, 256, 0, stream>>>(X, rowp, Fp, out, B, T);
}

// Round 3
// 47.266 us; speedup vs baseline: 13.1838x; 5.2387x over previous
//
#include <hip/hip_runtime.h>
#include <hip/hip_bf16.h>
#include <math.h>

#define NF 32
#define NH 8
#define NP 6

// ---------------- bn0 stats: one block per feature ----------------
__global__ __launch_bounds__(256) void bn0_stats_kernel(
    const float* __restrict__ src,
    const float* __restrict__ g,
    const float* __restrict__ b,
    float* __restrict__ scale,
    float* __restrict__ shift,
    int nrows)
{
    int f = blockIdx.x;
    int tid = threadIdx.x;
    float s = 0.f, sq = 0.f;
    for (int r = tid; r < nrows; r += 256) {
        float v = src[(size_t)r * NF + f];
        s += v; sq += v * v;
    }
    __shared__ float ls[256], lq[256];
    ls[tid] = s; lq[tid] = sq;
    __syncthreads();
    for (int st = 128; st > 0; st >>= 1) {
        if (tid < st) { ls[tid] += ls[tid + st]; lq[tid] += lq[tid + st]; }
        __syncthreads();
    }
    if (tid == 0) {
        float inv_n = 1.0f / (float)nrows;
        float m = ls[0] * inv_n;
        float var = lq[0] * inv_n - m * m;
        float sc = g[f] * rsqrtf(var + 1e-5f);
        scale[f] = sc;
        shift[f] = b[f] - m * sc;
    }
}

// ---------------- layer 1 + per-block bn1 partials ----------------
__global__ __launch_bounds__(256) void mlp1_kernel(
    const float* __restrict__ feat,
    const float* __restrict__ scale,
    const float* __restrict__ shift,
    const float* __restrict__ W1,
    const float* __restrict__ b1,
    float* __restrict__ h1,
    float* __restrict__ part,   // [nblocks][2][NH]
    int B)
{
    __shared__ float sW1[NH * NF], sb1[NH], ssc[NF], ssh[NF];
    int tid = threadIdx.x;
    if (tid < NH * NF) sW1[tid] = W1[tid];
    if (tid < NH) sb1[tid] = b1[tid];
    if (tid < NF) { ssc[tid] = scale[tid]; ssh[tid] = shift[tid]; }
    __syncthreads();

    int r = blockIdx.x * 256 + tid;
    float h[NH];
    if (r < B) {
        float x[NF];
#pragma unroll
        for (int i = 0; i < NF; i++)
            x[i] = feat[(size_t)r * NF + i] * ssc[i] + ssh[i];
#pragma unroll
        for (int o = 0; o < NH; o++) {
            float acc = sb1[o];
#pragma unroll
            for (int i = 0; i < NF; i++) acc = fmaf(sW1[o * NF + i], x[i], acc);
            h[o] = acc;
            h1[(size_t)r * NH + o] = acc;
        }
    } else {
#pragma unroll
        for (int o = 0; o < NH; o++) h[o] = 0.f;
    }

    // block reduction of sum & sumsq per feature
    __shared__ float ls[NH][256];
    __shared__ float lq[NH][256];
#pragma unroll
    for (int o = 0; o < NH; o++) { ls[o][tid] = h[o]; lq[o][tid] = h[o] * h[o]; }
    __syncthreads();
    for (int st = 128; st > 0; st >>= 1) {
        if (tid < st) {
#pragma unroll
            for (int o = 0; o < NH; o++) {
                ls[o][tid] += ls[o][tid + st];
                lq[o][tid] += lq[o][tid + st];
            }
        }
        __syncthreads();
    }
    if (tid < NH) {
        part[(size_t)blockIdx.x * 2 * NH + tid] = ls[tid][0];
        part[(size_t)blockIdx.x * 2 * NH + NH + tid] = lq[tid][0];
    }
}

// ---------------- layer 2 (+redundant bn1 finalize) + bn2 partials ----------------
__global__ __launch_bounds__(256) void mlp_mid_kernel(
    const float* __restrict__ hin,
    const float* __restrict__ part_in,   // [nb][2][NH]
    const float* __restrict__ bn_g,
    const float* __restrict__ bn_b,
    const float* __restrict__ W,
    const float* __restrict__ bb,
    float* __restrict__ hout,
    float* __restrict__ part_out,
    int B, int nb)
{
    __shared__ float sW[NH * NH], sb[NH], ssc[NH], ssh[NH];
    int tid = threadIdx.x;
    if (tid < NH * NH) sW[tid] = W[tid];
    if (tid >= 64 && tid < 64 + NH) sb[tid - 64] = bb[tid - 64];
    if (tid < NH) {
        float s = 0.f, q = 0.f;
        for (int c = 0; c < nb; c++) {
            s += part_in[(size_t)c * 2 * NH + tid];
            q += part_in[(size_t)c * 2 * NH + NH + tid];
        }
        float inv_n = 1.0f / (float)B;
        float m = s * inv_n;
        float var = q * inv_n - m * m;
        float sc = bn_g[tid] * rsqrtf(var + 1e-5f);
        ssc[tid] = sc;
        ssh[tid] = bn_b[tid] - m * sc;
    }
    __syncthreads();

    int r = blockIdx.x * 256 + tid;
    float h[NH];
    if (r < B) {
        float x[NH];
#pragma unroll
        for (int i = 0; i < NH; i++) {
            float v = hin[(size_t)r * NH + i] * ssc[i] + ssh[i];
            x[i] = fmaxf(v, 0.0f);
        }
#pragma unroll
        for (int o = 0; o < NH; o++) {
            float acc = sb[o];
#pragma unroll
            for (int i = 0; i < NH; i++) acc = fmaf(sW[o * NH + i], x[i], acc);
            h[o] = acc;
            hout[(size_t)r * NH + o] = acc;
        }
    } else {
#pragma unroll
        for (int o = 0; o < NH; o++) h[o] = 0.f;
    }

    __shared__ float ls[NH][256];
    __shared__ float lq[NH][256];
#pragma unroll
    for (int o = 0; o < NH; o++) { ls[o][tid] = h[o]; lq[o][tid] = h[o] * h[o]; }
    __syncthreads();
    for (int st = 128; st > 0; st >>= 1) {
        if (tid < st) {
#pragma unroll
            for (int o = 0; o < NH; o++) {
                ls[o][tid] += ls[o][tid + st];
                lq[o][tid] += lq[o][tid + st];
            }
        }
        __syncthreads();
    }
    if (tid < NH) {
        part_out[(size_t)blockIdx.x * 2 * NH + tid] = ls[tid][0];
        part_out[(size_t)blockIdx.x * 2 * NH + NH + tid] = lq[tid][0];
    }
}

// ---------------- layer 3 (+redundant bn2 finalize) + scan constants ----------------
__global__ __launch_bounds__(256) void params_kernel(
    const float* __restrict__ h2,
    const float* __restrict__ part_in,
    const float* __restrict__ bn_g,
    const float* __restrict__ bn_b,
    const float* __restrict__ W3,
    const float* __restrict__ b3,
    const float* __restrict__ pn,
    float* __restrict__ rowp,
    int B, int nb, int T)
{
    __shared__ float sW3[NP * NH], sb3[NP], spn[NP], ssc[NH], ssh[NH];
    int tid = threadIdx.x;
    if (tid < NP * NH) sW3[tid] = W3[tid];
    if (tid >= 64 && tid < 64 + NP) sb3[tid - 64] = b3[tid - 64];
    if (tid >= 96 && tid < 96 + NP) spn[tid - 96] = pn[tid - 96];
    if (tid < NH) {
        float s = 0.f, q = 0.f;
        for (int c = 0; c < nb; c++) {
            s += part_in[(size_t)c * 2 * NH + tid];
            q += part_in[(size_t)c * 2 * NH + NH + tid];
        }
        float inv_n = 1.0f / (float)B;
        float m = s * inv_n;
        float var = q * inv_n - m * m;
        float sc = bn_g[tid] * rsqrtf(var + 1e-5f);
        ssc[tid] = sc;
        ssh[tid] = bn_b[tid] - m * sc;
    }
    __syncthreads();

    int r = blockIdx.x * 256 + tid;
    if (r >= B) return;
    float x[NH];
#pragma unroll
    for (int i = 0; i < NH; i++) {
        float v = h2[(size_t)r * NH + i] * ssc[i] + ssh[i];
        x[i] = fmaxf(v, 0.0f);
    }
    const float lo[NP] = {0.5f, 0.01f, 0.0f, 0.0f, 0.0f, 0.01f};
    const float hi[NP] = {5.0f, 0.5f, 2.0f, 2.0f, 1.0f, 0.5f};
    float p[NP];
#pragma unroll
    for (int j = 0; j < NP; j++) {
        float cr = sb3[j] + spn[j];
#pragma unroll
        for (int i = 0; i < NH; i++) cr = fmaf(sW3[j * NH + i], x[i], cr);
        float sg = 1.0f / (1.0f + expf(-cr));
        p[j] = lo[j] + (hi[j] - lo[j]) * sg;
    }
    float f_start = p[0], f_inf = p[1], f_decay = p[2], f_T = p[3];
    float w_offset = p[4], w_T = p[5];
    float df = f_start - f_inf;
    const float LOG2_0p7 = -0.5145731728297583f;
    const float LOG2_0p1 = -3.3219280948873623f;
    const float LOG2_10 = 3.3219280948873623f;
    float log2base = LOG2_0p7 + f_decay * LOG2_0p1;
    float invden = 0.1f * exp2f(LOG2_10 * f_T);
    float k = log2base * invden / (float)T;
    float wscale = 1.0f / ((float)T * w_T);
    float wbias = -w_offset / w_T;
    float* rp = rowp + (size_t)r * 8;
    rp[0] = f_inf; rp[1] = df; rp[2] = k; rp[3] = wscale; rp[4] = wbias;
    rp[5] = 0.f; rp[6] = 0.f; rp[7] = 0.f;
}

// ==================== parallel scan: one wave per row ====================
// State s=(y1,y2); step t>=1: s = [[-a,0],[g,-a]] s + (u, b*u), g=b(1-a), u=b(x_t+x_{t-1})
// t==0 "reset": M=0, V=(x0,x0). Composites closed under [[P,0],[Q,P]] + (V1,V2).
__global__ __launch_bounds__(256) void scan_kernel(
    const float* __restrict__ X,
    const float* __restrict__ rowp,
    const float* __restrict__ Fp,
    float* __restrict__ out, int B, int T)
{
    const int lane = threadIdx.x & 63;
    const int r = blockIdx.x * 4 + (threadIdx.x >> 6);
    if (r >= B) return;

    const float* rp = rowp + (size_t)r * 8;
    const float f_inf = rp[0], df = rp[1], k = rp[2], wsc = rp[3], wb = rp[4];
    const float F = Fp[0];
    const float c = sqrtf(exp2f(1.0f / 3.0f) - 1.0f) * F * (1.0f / 3.14159265358979323846f);
    const float c2 = 2.0f * c;

    const int C = T >> 6;          // steps per lane (64)
    const int t0 = lane * C;
    const float* Xr = X + (size_t)r * T;
    const float4* Xr4 = reinterpret_cast<const float4*>(Xr + t0);

    const float ek = exp2f(k);

    // ---------- pass 1: per-lane affine composite ----------
    float P = 1.f, Q = 0.f, V1 = 0.f, V2 = 0.f;
    {
        float e = exp2f(k * (float)t0);
        float xp = (lane == 0) ? 0.f : Xr[t0 - 1];
        for (int j = 0; j < C / 4; j++) {
            float4 xq = Xr4[j];
            float xs[4] = {xq.x, xq.y, xq.z, xq.w};
#pragma unroll
            for (int m = 0; m < 4; m++) {
                int t = t0 + j * 4 + m;
                float x = xs[m];
                if (t == 0) {
                    P = 0.f; Q = 0.f; V1 = x; V2 = x;
                } else {
                    float ft = fmaf(df, e, f_inf);
                    float inv = __builtin_amdgcn_rcpf(ft + c);
                    float a = fmaf(-c2, inv, 1.0f);
                    float b = fmaf(-c, inv, 1.0f);
                    float u = b * (x + xp);
                    float g = b * c2 * inv;   // b*(1-a)
                    float Pn = -a * P;
                    float Qn = fmaf(g, P, -a * Q);
                    float V1n = fmaf(-a, V1, u);
                    float V2n = fmaf(g, V1, fmaf(-a, V2, b * u));
                    P = Pn; Q = Qn; V1 = V1n; V2 = V2n;
                }
                e *= ek;
                xp = x;
            }
        }
    }

    // ---------- inclusive scan across lanes (compose: mine after other) ----------
#pragma unroll
    for (int d = 1; d < 64; d <<= 1) {
        float Po = __shfl_up(P, d);
        float Qo = __shfl_up(Q, d);
        float V1o = __shfl_up(V1, d);
        float V2o = __shfl_up(V2, d);
        if (lane >= d) {
            float Pn = P * Po;
            float Qn = fmaf(Q, Po, P * Qo);
            float V1n = fmaf(P, V1o, V1);
            float V2n = fmaf(Q, V1o, fmaf(P, V2o, V2));
            P = Pn; Q = Qn; V1 = V1n; V2 = V2n;
        }
    }
    float y1 = __shfl_up(V1, 1);
    float y2 = __shfl_up(V2, 1);
    if (lane == 0) { y1 = 0.f; y2 = 0.f; }

    // ---------- pass 2: replay with real state, accumulate ----------
    float acc = 0.f, wsum = 0.f;
    {
        float e = exp2f(k * (float)t0);
        float E = expf(-(wsc * (float)t0 + wb));
        float er = expf(-wsc);
        float xp = (lane == 0) ? 0.f : Xr[t0 - 1];
        for (int j = 0; j < C / 4; j++) {
            float4 xq = Xr4[j];
            float xs[4] = {xq.x, xq.y, xq.z, xq.w};
#pragma unroll
            for (int m = 0; m < 4; m++) {
                int t = t0 + j * 4 + m;
                float x = xs[m];
                float w = __builtin_amdgcn_rcpf(1.0f + E);
                if (t == 0) {
                    y1 = x; y2 = x;
                } else {
                    float ft = fmaf(df, e, f_inf);
                    float inv = __builtin_amdgcn_rcpf(ft + c);
                    float a = fmaf(-c2, inv, 1.0f);
                    float b = fmaf(-c, inv, 1.0f);
                    float y1n = fmaf(b, x + xp, -a * y1);
                    float y2n = fmaf(b, y1n + y1, -a * y2);
                    y1 = y1n; y2 = y2n;
                }
                acc = fmaf(w, y2, acc);
                wsum += w;
                e *= ek;
                E *= er;
                xp = x;
            }
        }
    }

    // ---------- wave reduction ----------
#pragma unroll
    for (int d = 1; d < 64; d <<= 1) {
        acc += __shfl_xor(acc, d);
        wsum += __shfl_xor(wsum, d);
    }
    if (lane == 0) out[r] = acc / wsum;
}

extern "C" void kernel_launch(void* const* d_in, const int* in_sizes, int n_in,
                              void* d_out, int out_size, void* d_ws, size_t ws_size,
                              hipStream_t stream) {
    const float* X = (const float*)d_in[0];
    const float* features = (const float*)d_in[1];
    const float* Fp = (const float*)d_in[2];
    const float* bn0_g = (const float*)d_in[3];
    const float* bn0_b = (const float*)d_in[4];
    const float* W1 = (const float*)d_in[5];
    const float* b1 = (const float*)d_in[6];
    const float* bn1_g = (const float*)d_in[7];
    const float* bn1_b = (const float*)d_in[8];
    const float* W2 = (const float*)d_in[9];
    const float* b2 = (const float*)d_in[10];
    const float* bn2_g = (const float*)d_in[11];
    const float* bn2_b = (const float*)d_in[12];
    const float* W3 = (const float*)d_in[13];
    const float* b3 = (const float*)d_in[14];
    const float* pn = (const float*)d_in[15];
    float* out = (float*)d_out;

    const int B = in_sizes[1] / NF;      // 2048
    const int T = in_sizes[0] / B;       // 4096
    const int nb = (B + 255) / 256;      // 8

    float* ws = (float*)d_ws;
    float* sc0 = ws;                           // 32
    float* sh0 = ws + 32;                      // 32
    float* part1 = ws + 64;                    // nb*16
    float* part2 = part1 + (size_t)nb * 16;    // nb*16
    float* h1buf = part2 + (size_t)nb * 16;    // B*8
    float* h2buf = h1buf + (size_t)B * NH;     // B*8
    float* rowp  = h2buf + (size_t)B * NH;     // B*8

    bn0_stats_kernel<<<NF, 256, 0, stream>>>(features, bn0_g, bn0_b, sc0, sh0, B);
    mlp1_kernel<<<nb, 256, 0, stream>>>(features, sc0, sh0, W1, b1, h1buf, part1, B);
    mlp_mid_kernel<<<nb, 256, 0, stream>>>(h1buf, part1, bn1_g, bn1_b, W2, b2,
                                           h2buf, part2, B, nb);
    params_kernel<<<nb, 256, 0, stream>>>(h2buf, part2, bn2_g, bn2_b, W3, b3, pn,
                                          rowp, B, nb, T);
    scan_kernel<<<(B + 3) / 4, 256, 0, stream>>>(X, rowp, Fp, out, B, T);
}

// Round 4
// 41.500 us; speedup vs baseline: 15.0155x; 1.1389x over previous
//
#include <hip/hip_runtime.h>
#include <hip/hip_bf16.h>
#include <math.h>

#define NF 32
#define NH 8
#define NP 6

// ================= K1: per-feature mean + second-moment row =================
// block i computes mu[i] = E[f_i] and S[i][j] = E[f_i f_j] for all j.
__global__ __launch_bounds__(256) void moments_kernel(
    const float* __restrict__ feat,
    float* __restrict__ mu,     // [NF]
    float* __restrict__ S,      // [NF][NF]
    int B)
{
    const int i = blockIdx.x;
    const int tid = threadIdx.x;
    float s = 0.f;
    float sj[NF];
#pragma unroll
    for (int j = 0; j < NF; j++) sj[j] = 0.f;

    for (int r = tid; r < B; r += 256) {
        const float* row = feat + (size_t)r * NF;
        const float4* row4 = (const float4*)row;
        float fi = row[i];
        s += fi;
#pragma unroll
        for (int jq = 0; jq < NF / 4; jq++) {
            float4 q = row4[jq];
            sj[4*jq+0] = fmaf(fi, q.x, sj[4*jq+0]);
            sj[4*jq+1] = fmaf(fi, q.y, sj[4*jq+1]);
            sj[4*jq+2] = fmaf(fi, q.z, sj[4*jq+2]);
            sj[4*jq+3] = fmaf(fi, q.w, sj[4*jq+3]);
        }
    }
    // wave butterfly reduce (33 values)
#pragma unroll
    for (int d = 1; d < 64; d <<= 1) {
        s += __shfl_xor(s, d);
#pragma unroll
        for (int j = 0; j < NF; j++) sj[j] += __shfl_xor(sj[j], d);
    }
    __shared__ float red[4][NF + 1];
    const int wv = tid >> 6, lane = tid & 63;
    if (lane == 0) {
#pragma unroll
        for (int j = 0; j < NF; j++) red[wv][j] = sj[j];
        red[wv][NF] = s;
    }
    __syncthreads();
    if (tid < NF + 1) {
        float tot = red[0][tid] + red[1][tid] + red[2][tid] + red[3][tid];
        tot *= (1.0f / (float)B);
        if (tid < NF) S[(size_t)i * NF + tid] = tot;
        else mu[i] = tot;
    }
}

// ====== K2: analytic bn0+bn1 fold -> relu -> layer2 -> h2 + bn2 partials ======
__global__ __launch_bounds__(256) void mlp_kernel(
    const float* __restrict__ feat,
    const float* __restrict__ mu,
    const float* __restrict__ S,
    const float* __restrict__ bn0_g, const float* __restrict__ bn0_b,
    const float* __restrict__ W1, const float* __restrict__ b1,
    const float* __restrict__ bn1_g, const float* __restrict__ bn1_b,
    const float* __restrict__ W2, const float* __restrict__ b2,
    float* __restrict__ h2buf,
    float* __restrict__ part,   // [nb][2][NH]
    int B)
{
    __shared__ float ssc0[NF], ssh0[NF], smu[NF];
    __shared__ float w1p[NH][NF];
    __shared__ float Wf[NH][NF];
    __shared__ float bfold[NH];
    __shared__ float sW2[NH * NH], sb2[NH];
    __shared__ float vgrp[8];
    __shared__ float ssc1[NH];

    const int tid = threadIdx.x;
    if (tid < NF) {
        float m = mu[tid];
        smu[tid] = m;
        float var = S[(size_t)tid * NF + tid] - m * m;
        float sc = bn0_g[tid] * rsqrtf(var + 1e-5f);
        ssc0[tid] = sc;
        ssh0[tid] = bn0_b[tid] - m * sc;
    }
    if (tid >= 64 && tid < 64 + NH * NH) sW2[tid - 64] = W2[tid - 64];
    if (tid >= 128 && tid < 128 + NH) sb2[tid - 128] = b2[tid - 128];
    __syncthreads();
    {
        const int o = tid >> 5, i = tid & 31;
        w1p[o][i] = W1[o * NF + i] * ssc0[i];
    }
    __syncthreads();
    // var(h1_o) = sum_ij w1p[o][i] Cov[i][j] w1p[o][j]
    float vacc;
    {
        const int o = tid >> 5, i = tid & 31;
        float mi = smu[i];
        float acc = 0.f;
#pragma unroll
        for (int j = 0; j < NF; j++)
            acc = fmaf(S[(size_t)i * NF + j] - mi * smu[j], w1p[o][j], acc);
        vacc = acc * w1p[o][i];
    }
#pragma unroll
    for (int d = 1; d < 32; d <<= 1) vacc += __shfl_xor(vacc, d, 32);
    if ((tid & 31) == 0) vgrp[tid >> 5] = vacc;
    __syncthreads();
    if (tid < NH) {
        const int o = tid;
        float c1 = b1[o];
#pragma unroll
        for (int i = 0; i < NF; i++) c1 = fmaf(W1[o * NF + i], ssh0[i], c1);
        float m1 = c1;
#pragma unroll
        for (int i = 0; i < NF; i++) m1 = fmaf(w1p[o][i], smu[i], m1);
        float var1 = vgrp[o];
        float sc1 = bn1_g[o] * rsqrtf(var1 + 1e-5f);
        float sh1 = bn1_b[o] - m1 * sc1;
        ssc1[o] = sc1;
        bfold[o] = fmaf(sc1, c1, sh1);
    }
    __syncthreads();
    {
        const int o = tid >> 5, i = tid & 31;
        Wf[o][i] = ssc1[o] * w1p[o][i];
    }
    __syncthreads();

    const int r = blockIdx.x * 256 + tid;
    float h[NH];
    if (r < B) {
        float x[NF];
        const float4* row4 = (const float4*)(feat + (size_t)r * NF);
#pragma unroll
        for (int jq = 0; jq < NF / 4; jq++) {
            float4 q = row4[jq];
            x[4*jq+0] = q.x; x[4*jq+1] = q.y; x[4*jq+2] = q.z; x[4*jq+3] = q.w;
        }
        float x2[NH];
#pragma unroll
        for (int o = 0; o < NH; o++) {
            float z = bfold[o];
#pragma unroll
            for (int i = 0; i < NF; i++) z = fmaf(Wf[o][i], x[i], z);
            x2[o] = fmaxf(z, 0.f);
        }
#pragma unroll
        for (int o = 0; o < NH; o++) {
            float acc = sb2[o];
#pragma unroll
            for (int i = 0; i < NH; i++) acc = fmaf(sW2[o * NH + i], x2[i], acc);
            h[o] = acc;
            h2buf[(size_t)r * NH + o] = acc;
        }
    } else {
#pragma unroll
        for (int o = 0; o < NH; o++) h[o] = 0.f;
    }

    __shared__ float ls[NH][256];
    __shared__ float lq[NH][256];
#pragma unroll
    for (int o = 0; o < NH; o++) { ls[o][tid] = h[o]; lq[o][tid] = h[o] * h[o]; }
    __syncthreads();
    for (int st = 128; st > 0; st >>= 1) {
        if (tid < st) {
#pragma unroll
            for (int o = 0; o < NH; o++) {
                ls[o][tid] += ls[o][tid + st];
                lq[o][tid] += lq[o][tid + st];
            }
        }
        __syncthreads();
    }
    if (tid < NH) {
        part[(size_t)blockIdx.x * 2 * NH + tid] = ls[tid][0];
        part[(size_t)blockIdx.x * 2 * NH + NH + tid] = lq[tid][0];
    }
}

// ========= K3: bn2 finalize + params + SINGLE-PASS parallel scan =========
// Chunk composite [[P,0],[Q,P]] + (V1,V2); accumulator sensitivities:
// sum_t w_t y2_t (chunk) = A1*y1_in + A2*y2_in + A0.
__global__ __launch_bounds__(256) void scan_kernel(
    const float* __restrict__ X,
    const float* __restrict__ h2buf,
    const float* __restrict__ part,   // [nb][2][NH]
    const float* __restrict__ bn2_g, const float* __restrict__ bn2_b,
    const float* __restrict__ W3, const float* __restrict__ b3,
    const float* __restrict__ pn,
    const float* __restrict__ Fp,
    float* __restrict__ out, int B, int T, int nb)
{
    __shared__ float ssc2[NH], ssh2[NH];
    __shared__ float sW3[NP * NH], sb3[NP], spn[NP];
    __shared__ float sF;
    const int tid = threadIdx.x;
    if (tid < NH) {
        float s = 0.f, q = 0.f;
        for (int c = 0; c < nb; c++) {
            s += part[(size_t)c * 2 * NH + tid];
            q += part[(size_t)c * 2 * NH + NH + tid];
        }
        float inv_n = 1.0f / (float)B;
        float m = s * inv_n;
        float var = q * inv_n - m * m;
        float sc = bn2_g[tid] * rsqrtf(var + 1e-5f);
        ssc2[tid] = sc;
        ssh2[tid] = bn2_b[tid] - m * sc;
    }
    if (tid >= 64 && tid < 64 + NP * NH) sW3[tid - 64] = W3[tid - 64];
    if (tid >= 128 && tid < 128 + NP) sb3[tid - 128] = b3[tid - 128];
    if (tid >= 160 && tid < 160 + NP) spn[tid - 160] = pn[tid - 160];
    if (tid == 192) sF = Fp[0];
    __syncthreads();

    const int lane = tid & 63;
    const int r = blockIdx.x * 4 + (tid >> 6);
    if (r >= B) return;

    // ---- params (lane-redundant, trivial) ----
    float x3[NH];
#pragma unroll
    for (int i = 0; i < NH; i++) {
        float v = h2buf[(size_t)r * NH + i] * ssc2[i] + ssh2[i];
        x3[i] = fmaxf(v, 0.0f);
    }
    const float lo[NP] = {0.5f, 0.01f, 0.0f, 0.0f, 0.0f, 0.01f};
    const float hi[NP] = {5.0f, 0.5f, 2.0f, 2.0f, 1.0f, 0.5f};
    float p[NP];
#pragma unroll
    for (int j = 0; j < NP; j++) {
        float cr = sb3[j] + spn[j];
#pragma unroll
        for (int i = 0; i < NH; i++) cr = fmaf(sW3[j * NH + i], x3[i], cr);
        float sg = 1.0f / (1.0f + expf(-cr));
        p[j] = lo[j] + (hi[j] - lo[j]) * sg;
    }
    const float f_inf = p[1], df = p[0] - p[1];
    const float LOG2_0p7 = -0.5145731728297583f;
    const float LOG2_0p1 = -3.3219280948873623f;
    const float LOG2_10 = 3.3219280948873623f;
    float log2base = LOG2_0p7 + p[2] * LOG2_0p1;
    float invden = 0.1f * exp2f(LOG2_10 * p[3]);
    const float k = log2base * invden / (float)T;
    const float wsc = 1.0f / ((float)T * p[5]);
    const float wb = -p[4] / p[5];
    const float c = sqrtf(exp2f(1.0f / 3.0f) - 1.0f) * sF * (1.0f / 3.14159265358979323846f);
    const float c2 = 2.0f * c;

    // ---- single pass: composite + accumulator sensitivities ----
    const int C = T >> 6;
    const int t0 = lane * C;
    const float* Xr = X + (size_t)r * T;
    const float4* Xr4 = (const float4*)(Xr + t0);
    const float ek = exp2f(k);
    const float er = expf(-wsc);

    float e = exp2f(k * (float)t0);
    float E = expf(-(wsc * (float)t0 + wb));
    float xp = (lane == 0) ? 0.f : Xr[t0 - 1];

    float P = 1.f, Q = 0.f, V1 = 0.f, V2 = 0.f;
    float A1 = 0.f, A2 = 0.f, A0 = 0.f, wsum = 0.f;

    for (int j = 0; j < C / 4; j++) {
        float4 xq = Xr4[j];
        float xs[4] = {xq.x, xq.y, xq.z, xq.w};
#pragma unroll
        for (int m = 0; m < 4; m++) {
            const int t = t0 + j * 4 + m;
            const float x = xs[m];
            if (t == 0) {
                P = 0.f; Q = 0.f; V1 = x; V2 = x;
            } else {
                float ft = fmaf(df, e, f_inf);
                float inv = __builtin_amdgcn_rcpf(ft + c);
                float a = fmaf(-c2, inv, 1.0f);
                float b = fmaf(-c, inv, 1.0f);
                float u = b * (x + xp);
                float g = b * c2 * inv;    // b*(1-a)
                float Pn = -a * P;
                float Qn = fmaf(g, P, -a * Q);
                float V1n = fmaf(-a, V1, u);
                float V2n = fmaf(g, V1, fmaf(-a, V2, b * u));
                P = Pn; Q = Qn; V1 = V1n; V2 = V2n;
            }
            float w = __builtin_amdgcn_rcpf(1.0f + E);
            A1 = fmaf(w, Q, A1);
            A2 = fmaf(w, P, A2);
            A0 = fmaf(w, V2, A0);
            wsum += w;
            e *= ek;
            E *= er;
            xp = x;
        }
    }

    // ---- inclusive lane scan of (P,Q,V1,V2) ----
#pragma unroll
    for (int d = 1; d < 64; d <<= 1) {
        float Po = __shfl_up(P, d);
        float Qo = __shfl_up(Q, d);
        float V1o = __shfl_up(V1, d);
        float V2o = __shfl_up(V2, d);
        if (lane >= d) {
            float Pn = P * Po;
            float Qn = fmaf(Q, Po, P * Qo);
            float V1n = fmaf(P, V1o, V1);
            float V2n = fmaf(Q, V1o, fmaf(P, V2o, V2));
            P = Pn; Q = Qn; V1 = V1n; V2 = V2n;
        }
    }
    // exclusive incoming state per lane
    float y1in = __shfl_up(V1, 1);
    float y2in = __shfl_up(V2, 1);
    if (lane == 0) { y1in = 0.f; y2in = 0.f; }

    float contrib = fmaf(A1, y1in, fmaf(A2, y2in, A0));
#pragma unroll
    for (int d = 1; d < 64; d <<= 1) {
        contrib += __shfl_xor(contrib, d);
        wsum += __shfl_xor(wsum, d);
    }
    if (lane == 0) out[r] = contrib / wsum;
}

extern "C" void kernel_launch(void* const* d_in, const int* in_sizes, int n_in,
                              void* d_out, int out_size, void* d_ws, size_t ws_size,
                              hipStream_t stream) {
    const float* X = (const float*)d_in[0];
    const float* features = (const float*)d_in[1];
    const float* Fp = (const float*)d_in[2];
    const float* bn0_g = (const float*)d_in[3];
    const float* bn0_b = (const float*)d_in[4];
    const float* W1 = (const float*)d_in[5];
    const float* b1 = (const float*)d_in[6];
    const float* bn1_g = (const float*)d_in[7];
    const float* bn1_b = (const float*)d_in[8];
    const float* W2 = (const float*)d_in[9];
    const float* b2 = (const float*)d_in[10];
    const float* bn2_g = (const float*)d_in[11];
    const float* bn2_b = (const float*)d_in[12];
    const float* W3 = (const float*)d_in[13];
    const float* b3 = (const float*)d_in[14];
    const float* pn = (const float*)d_in[15];
    float* out = (float*)d_out;

    const int B = in_sizes[1] / NF;      // 2048
    const int T = in_sizes[0] / B;       // 4096
    const int nb = (B + 255) / 256;      // 8

    float* ws = (float*)d_ws;
    float* mu = ws;                           // 32
    float* S = ws + NF;                       // 32*32
    float* part = S + NF * NF;                // nb*16
    float* h2buf = part + (size_t)nb * 16;    // B*8

    moments_kernel<<<NF, 256, 0, stream>>>(features, mu, S, B);
    mlp_kernel<<<nb, 256, 0, stream>>>(features, mu, S, bn0_g, bn0_b, W1, b1,
                                       bn1_g, bn1_b, W2, b2, h2buf, part, B);
    scan_kernel<<<(B + 3) / 4, 256, 0, stream>>>(X, h2buf, part, bn2_g, bn2_b,
                                                 W3, b3, pn, Fp, out, B, T, nb);
}